// Round 4
// baseline (319.931 us; speedup 1.0000x reference)
//
#include <hip/hip_runtime.h>
#include <hip/hip_bf16.h>

#define B_  32
#define N_  2048
#define M_  2048
#define D_  128

typedef __attribute__((ext_vector_type(4)))  float f32x4;
typedef __attribute__((ext_vector_type(8)))  short bf16x8;

// log2(e) / sqrt(128): softmax in exp2 domain; folded into Q's bf16 cast.
static constexpr float SCALE2 = 1.4426950408889634f / 11.313708498984761f;

__device__ __forceinline__ unsigned short f2bf(float x) {
  union { float f; unsigned u; } c; c.f = x;
  unsigned u = c.u;
  return (unsigned short)((u + 0x7FFFu + ((u >> 16) & 1u)) >> 16);  // RNE
}

__device__ __forceinline__ unsigned pk2bf(float a, float b) {
  float2 f2; f2.x = a; f2.y = b;
  __hip_bfloat162 h = __float22bfloat162_rn(f2);   // v_cvt_pk_bf16_f32
  union { __hip_bfloat162 h; unsigned u; } c; c.h = h;
  return c.u;
}

// 8 f32 -> bf16x8 with scale, identical op order (mul, then RNE pack) to the
// cast path so colstats' S is bitwise-identical to attn's.
__device__ __forceinline__ bf16x8 pack8(f32x4 lo, f32x4 hi, float s) {
  union { bf16x8 v; unsigned u[4]; } c;
  c.u[0] = pk2bf(lo[0] * s, lo[1] * s);
  c.u[1] = pk2bf(lo[2] * s, lo[3] * s);
  c.u[2] = pk2bf(hi[0] * s, hi[1] * s);
  c.u[3] = pk2bf(hi[2] * s, hi[3] * s);
  return c.v;
}

__device__ __forceinline__ float fexp2(float x) {
#if __has_builtin(__builtin_amdgcn_exp2f)
  return __builtin_amdgcn_exp2f(x);
#else
  float r; asm("v_exp_f32 %0, %1" : "=v"(r) : "v"(x)); return r;
#endif
}
__device__ __forceinline__ float flog2(float x) {
#if __has_builtin(__builtin_amdgcn_logf)
  return __builtin_amdgcn_logf(x);
#else
  float r; asm("v_log_f32 %0, %1" : "=v"(r) : "v"(x)); return r;
#endif
}

// async global->LDS, 16B per lane; LDS dest = wave-uniform base + lane*16
__device__ __forceinline__ void gl2lds16(const void* gp, void* lp) {
  __builtin_amdgcn_global_load_lds(
      (const __attribute__((address_space(1))) unsigned int*)gp,
      (__attribute__((address_space(3))) unsigned int*)lp, 16, 0, 0);
}

// ---------- fused front-end (one dispatch) ----------
// blocks [0,1024):      colstats on RAW f32 Q/K (no LDS, no barriers, regs only)
// blocks [1024,3072):   V transpose f32 -> bf16 Vt
// blocks [3072,19456):  Q cast (SCALE2) / K cast to bf16
// colstats reads f32 and converts in-register with the same pk2bf sequence the
// cast blocks use -> S is bitwise-identical to attn's; no dependency between
// branches, so cast traffic overlaps colstats MFMA across the grid.
// colsum zero-init is a hipMemsetAsync before this kernel.
__global__ __launch_bounds__(256, 3) void fused1_kernel(
    const float* __restrict__ Q, const float* __restrict__ K,
    const float* __restrict__ V, unsigned short* __restrict__ Qb,
    unsigned short* __restrict__ Kb, unsigned short* __restrict__ Vt,
    float* __restrict__ colsum) {
  const int blk = blockIdx.x;

  if (blk < 1024) {
    // ---- colstats: colsum[b][m] += sum_{n in quarter} 2^(s2[n,m]-16) ----
    // id = x*128 + (4b+y): id%8 == (4b+y)%8 so the 8 m-blocks sharing a
    // (b, n-quarter) Q stripe co-reside on one XCD (L2 serves the 4-wave
    // x 8-block read redundancy). 64 m per wave (kf = 64 VGPRs), 512 n.
    const int x    = blk >> 7;            // m-block 0..7
    const int q    = blk & 127;
    const int b    = q >> 2;
    const int y    = q & 3;               // n-quarter
    const int lane = threadIdx.x & 63;
    const int l15  = lane & 15;
    const int quad = lane >> 4;
    const int mw   = x * 256 + (threadIdx.x >> 6) * 64;
    const int nbase = y * (N_ / 4);

    // B-operand: B[col=m=mw+cg*16+l15][k=quad*8+j (+kc*32)] — from f32 K
    bf16x8 kf[4][4];
    #pragma unroll
    for (int cg = 0; cg < 4; ++cg) {
      const float* Kr = K + ((size_t)b * M_ + mw + cg * 16 + l15) * D_ + quad * 8;
      #pragma unroll
      for (int kc = 0; kc < 4; ++kc) {
        f32x4 lo = *reinterpret_cast<const f32x4*>(Kr + kc * 32);
        f32x4 hi = *reinterpret_cast<const f32x4*>(Kr + kc * 32 + 4);
        kf[cg][kc] = pack8(lo, hi, 1.0f);
      }
    }

    // A-operand rows: A[row=n=ng*16+l15][k=quad*8+j (+kc*32)] — from f32 Q
    const float* Qr = Q + ((size_t)b * N_ + nbase + l15) * D_ + quad * 8;

    float psum[4] = {0.f, 0.f, 0.f, 0.f};
    for (int ng = 0; ng < 32; ++ng) {
      const float* qp = Qr + (size_t)ng * (16 * D_);
      bf16x8 af[4];
      #pragma unroll
      for (int kc = 0; kc < 4; ++kc) {
        f32x4 lo = *reinterpret_cast<const f32x4*>(qp + kc * 32);
        f32x4 hi = *reinterpret_cast<const f32x4*>(qp + kc * 32 + 4);
        af[kc] = pack8(lo, hi, SCALE2);
      }
      f32x4 acc[4] = {{0.f,0.f,0.f,0.f}, {0.f,0.f,0.f,0.f},
                      {0.f,0.f,0.f,0.f}, {0.f,0.f,0.f,0.f}};
      __builtin_amdgcn_s_setprio(1);
      #pragma unroll
      for (int kc = 0; kc < 4; ++kc)
        #pragma unroll
        for (int cg = 0; cg < 4; ++cg)
          acc[cg] = __builtin_amdgcn_mfma_f32_16x16x32_bf16(
              af[kc], kf[cg][kc], acc[cg], 0, 0, 0);
      __builtin_amdgcn_s_setprio(0);
      #pragma unroll
      for (int cg = 0; cg < 4; ++cg)
        psum[cg] += fexp2(acc[cg][0] - 16.f) + fexp2(acc[cg][1] - 16.f) +
                    fexp2(acc[cg][2] - 16.f) + fexp2(acc[cg][3] - 16.f);
    }
    // reduce over quad (rows n live across quads); columns m at quad==0 lanes
    #pragma unroll
    for (int cg = 0; cg < 4; ++cg) {
      psum[cg] += __shfl_xor(psum[cg], 16);
      psum[cg] += __shfl_xor(psum[cg], 32);
    }
    if (quad == 0) {
      #pragma unroll
      for (int cg = 0; cg < 4; ++cg)
        atomicAdd(colsum + (size_t)b * M_ + mw + cg * 16 + l15, psum[cg]);
    }
    return;
  }

  if (blk < 3072) {
    // ---- V transpose: idx -> (b, m0, d0); 2048 blocks = 32 x 2 x 32 ----
    const int idx = blk - 1024;
    const int b  = idx >> 6;
    const int m0 = ((idx >> 1) & 31) * 64;
    const int d0 = (idx & 1) * 64;
    __shared__ float t[64][65];
    const int tid = threadIdx.x;
    const int r = tid >> 2;   // 0..63
    const int c = tid & 3;    // 0..3
    const float* src = V + ((size_t)b * M_ + (m0 + r)) * D_ + d0 + c * 16;
    #pragma unroll
    for (int i = 0; i < 4; ++i) {
      float4 v = reinterpret_cast<const float4*>(src)[i];
      t[r][c * 16 + i * 4 + 0] = v.x;
      t[r][c * 16 + i * 4 + 1] = v.y;
      t[r][c * 16 + i * 4 + 2] = v.z;
      t[r][c * 16 + i * 4 + 3] = v.w;
    }
    __syncthreads();
    ushort4 ob[4];
    #pragma unroll
    for (int i = 0; i < 4; ++i) {
      ob[i].x = f2bf(t[c * 16 + i * 4 + 0][r]);
      ob[i].y = f2bf(t[c * 16 + i * 4 + 1][r]);
      ob[i].z = f2bf(t[c * 16 + i * 4 + 2][r]);
      ob[i].w = f2bf(t[c * 16 + i * 4 + 3][r]);
    }
    ushort4* dst = reinterpret_cast<ushort4*>(
        Vt + ((size_t)b * D_ + d0 + r) * M_ + m0 + c * 16);
    #pragma unroll
    for (int i = 0; i < 4; ++i) dst[i] = ob[i];
    return;
  }

  // ---- Q/K casts: 16B load / 8B store per thread ----
  const int r2 = blk - 3072;
  const bool isK = r2 >= 8192;
  const int i = (isK ? r2 - 8192 : r2) * 256 + threadIdx.x;  // float4 idx < 2^21
  const float4* src = reinterpret_cast<const float4*>(isK ? K : Q);
  uint2* dst = reinterpret_cast<uint2*>(isK ? Kb : Qb);
  const float sc = isK ? 1.0f : SCALE2;
  const float4 v = src[i];
  uint2 o;
  o.x = pk2bf(v.x * sc, v.y * sc);
  o.y = pk2bf(v.z * sc, v.w * sc);
  dst[i] = o;
}

// ---------- pass 2: O[n,d] = sum_m 2^(s2[n,m]-cml[m]) * Vt[d,m] ----------
// EXACT v9 compute (proven 87.9us, MfmaUtil 33%, FETCH 24.7MB). 512 blocks,
// XCD-swizzled (id%8==b%8). 64-m chunks, double-buffered K/V LDS, 2-phase
// schedule, one barrier per chunk, setprio around MFMA clusters.
__global__ __launch_bounds__(256, 2) void attn_v9_kernel(
    const unsigned short* __restrict__ Qb, const unsigned short* __restrict__ Kb,
    const unsigned short* __restrict__ Vt, const float* __restrict__ colsum,
    float* __restrict__ out) {
  const int id   = blockIdx.x;        // 0..511
  const int b    = id & 31;
  const int xq   = id >> 5;           // n-block 0..15
  const int wv   = threadIdx.x >> 6;  // 0..3
  const int lane = threadIdx.x & 63;
  const int l15  = lane & 15;
  const int quad = lane >> 4;
  const int nq   = xq * 128 + wv * 32;

  __shared__ unsigned short kbuf[2][64 * 128];  // 2x16 KB: rows m (256B), chunk c^(m&15)
  __shared__ unsigned short vbuf[2][128 * 64];  // 2x16 KB: rows d (128B), chunk c^(d&7)
  __shared__ unsigned short pbuf[4][32 * 40];   // 10 KB: per-wave P^T [n][m32], stride 80B
  __shared__ float cmlb[2][64];                 // per-chunk log2 column denominators

  // Q B-operand: B[col=n=ng*16+l15][k=quad*8+j (+kc*32)] — loop invariant
  bf16x8 qf[2][4];
  #pragma unroll
  for (int ng = 0; ng < 2; ++ng) {
    const unsigned short* Qr =
        Qb + ((size_t)b * N_ + nq + ng * 16 + l15) * D_ + quad * 8;
    #pragma unroll
    for (int kc = 0; kc < 4; ++kc)
      qf[ng][kc] = *reinterpret_cast<const bf16x8*>(Qr + kc * 32);
  }

  // hoisted LDS bases (u16 units)
  const unsigned short* pk[4];   // K read: + cb*8192 + sub*4096 + cg*2048
  #pragma unroll
  for (int kc = 0; kc < 4; ++kc)
    pk[kc] = kbuf[0] + l15 * 128 + (((kc * 4 + quad) ^ l15) * 8);
  const unsigned short* pv[2];   // V read: + cb*8192 + dt*1024
  #pragma unroll
  for (int sub = 0; sub < 2; ++sub)
    pv[sub] = vbuf[0] + l15 * 64 + (((sub * 4 + quad) ^ (l15 & 7)) * 8);
  unsigned short* pww[2];        // P write: + cg*16
  const unsigned short* pwr[2];  // P read
  #pragma unroll
  for (int ng = 0; ng < 2; ++ng) {
    pww[ng] = pbuf[wv] + (ng * 16 + l15) * 40 + quad * 4;
    pwr[ng] = pbuf[wv] + (ng * 16 + l15) * 40 + quad * 8;
  }

  // running DMA source ptrs (4 K + 4 V slots/thread), constant LDS dests
  const unsigned short* kg[4]; unsigned short* kl[4];
  const unsigned short* vg[4]; unsigned short* vl[4];
  #pragma unroll
  for (int i = 0; i < 4; ++i) {
    int s = i * 256 + threadIdx.x;               // 16B slot 0..1023
    int rk = s >> 4, ck = (s & 15) ^ (rk & 15);
    kg[i] = Kb + ((size_t)b * M_ + rk) * D_ + ck * 8;
    kl[i] = kbuf[0] + (size_t)s * 8;
    int rv = s >> 3, cv = (s & 7) ^ (rv & 7);
    vg[i] = Vt + ((size_t)b * D_ + rv) * M_ + cv * 8;
    vl[i] = vbuf[0] + (size_t)s * 8;
  }

  const float* csb = colsum + (size_t)b * M_;

  f32x4 o[2][8];
  #pragma unroll
  for (int ng = 0; ng < 2; ++ng)
    #pragma unroll
    for (int dt = 0; dt < 8; ++dt) o[ng][dt] = (f32x4){0.f, 0.f, 0.f, 0.f};

#define AT_STAGE(nb, chunk)                                                   \
  { _Pragma("unroll")                                                         \
    for (int i = 0; i < 4; ++i) {                                             \
      gl2lds16(kg[i], kl[i] + (nb) * (64 * 128));                             \
      kg[i] += 64 * D_;                                                       \
      gl2lds16(vg[i], vl[i] + (nb) * (128 * 64));                             \
      vg[i] += 64;                                                            \
    }                                                                         \
    if (threadIdx.x < 64)                                                     \
      cmlb[nb][threadIdx.x] =                                                 \
          flog2(csb[(chunk) * 64 + threadIdx.x]) + 16.f; }

#define AT_COMPUTE(cb)                                                        \
  { _Pragma("unroll")                                                         \
    for (int sub = 0; sub < 2; ++sub) {                                       \
      /* QK^T (S^T): sacc[cg][ng]: row m=sub*32+cg*16+quad*4+r, col n */      \
      f32x4 sacc[2][2] = {{{0.f,0.f,0.f,0.f},{0.f,0.f,0.f,0.f}},              \
                          {{0.f,0.f,0.f,0.f},{0.f,0.f,0.f,0.f}}};             \
      __builtin_amdgcn_s_setprio(1);                                          \
      _Pragma("unroll")                                                       \
      for (int kc = 0; kc < 4; ++kc) {                                        \
        _Pragma("unroll")                                                     \
        for (int cg = 0; cg < 2; ++cg) {                                      \
          bf16x8 kfr = *reinterpret_cast<const bf16x8*>(                      \
              pk[kc] + (cb) * (64 * 128) + sub * 4096 + cg * 2048);           \
          sacc[cg][0] = __builtin_amdgcn_mfma_f32_16x16x32_bf16(              \
              kfr, qf[0][kc], sacc[cg][0], 0, 0, 0);                          \
          sacc[cg][1] = __builtin_amdgcn_mfma_f32_16x16x32_bf16(              \
              kfr, qf[1][kc], sacc[cg][1], 0, 0, 0);                          \
        }                                                                     \
      }                                                                       \
      __builtin_amdgcn_s_setprio(0);                                          \
      /* normalized P: w = 2^(s2 - cml[m]); packed b64 of 4 consecutive m */  \
      _Pragma("unroll")                                                       \
      for (int cg = 0; cg < 2; ++cg) {                                        \
        float4 cm4 = *reinterpret_cast<const float4*>(                        \
            &cmlb[cb][sub * 32 + cg * 16 + quad * 4]);                        \
        _Pragma("unroll")                                                     \
        for (int ng = 0; ng < 2; ++ng) {                                      \
          uint2 w;                                                            \
          w.x = pk2bf(fexp2(sacc[cg][ng][0] - cm4.x),                         \
                      fexp2(sacc[cg][ng][1] - cm4.y));                        \
          w.y = pk2bf(fexp2(sacc[cg][ng][2] - cm4.z),                         \
                      fexp2(sacc[cg][ng][3] - cm4.w));                        \
          *reinterpret_cast<uint2*>(pww[ng] + cg * 16) = w;                   \
        }                                                                     \
      }                                                                       \
      /* P A-frags (same-wave LDS RAW; lgkmcnt ordered) */                    \
      bf16x8 pa0 = *reinterpret_cast<const bf16x8*>(pwr[0]);                  \
      bf16x8 pa1 = *reinterpret_cast<const bf16x8*>(pwr[1]);                  \
      __builtin_amdgcn_s_setprio(1);                                          \
      _Pragma("unroll")                                                       \
      for (int dt = 0; dt < 8; ++dt) {                                        \
        bf16x8 vfr = *reinterpret_cast<const bf16x8*>(                        \
            pv[sub] + (cb) * (128 * 64) + dt * 1024);                         \
        o[0][dt] = __builtin_amdgcn_mfma_f32_16x16x32_bf16(                   \
            pa0, vfr, o[0][dt], 0, 0, 0);                                     \
        o[1][dt] = __builtin_amdgcn_mfma_f32_16x16x32_bf16(                   \
            pa1, vfr, o[1][dt], 0, 0, 0);                                     \
      }                                                                       \
      __builtin_amdgcn_s_setprio(0);                                          \
    } }

  AT_STAGE(0, 0);
  __syncthreads();
  #pragma unroll 1
  for (int it = 0; it < 32; it += 2) {
    AT_STAGE(1, it + 1);                       // prefetch while computing cur
    AT_COMPUTE(0);
    __syncthreads();                           // next chunk landed; buf0 free
    if (it + 2 < 32) AT_STAGE(0, it + 2);
    AT_COMPUTE(1);
    __syncthreads();
  }
#undef AT_STAGE
#undef AT_COMPUTE

  // epilogue: o[ng][dt][r] = O[nq + ng*16 + quad*4 + r][dt*16 + l15]
  #pragma unroll
  for (int ng = 0; ng < 2; ++ng)
    #pragma unroll
    for (int dt = 0; dt < 8; ++dt)
      #pragma unroll
      for (int r = 0; r < 4; ++r)
        out[((size_t)b * N_ + nq + ng * 16 + quad * 4 + r) * D_ + dt * 16 + l15] =
            o[ng][dt][r];
}

extern "C" void kernel_launch(void* const* d_in, const int* in_sizes, int n_in,
                              void* d_out, int out_size, void* d_ws, size_t ws_size,
                              hipStream_t stream) {
  const float* Q = (const float*)d_in[0];
  const float* K = (const float*)d_in[1];
  const float* V = (const float*)d_in[2];
  float* out = (float*)d_out;

  const size_t elems = (size_t)B_ * N_ * D_;   // 8,388,608 per tensor
  unsigned short* Qb = (unsigned short*)d_ws;                  // 16 MB
  unsigned short* Kb = Qb + elems;                             // 16 MB
  unsigned short* Vt = Kb + elems;                             // 16 MB
  float* colsum = (float*)(Vt + elems);                        // 256 KB
  // total ws use ~= 48.3 MB (proven safe)

  hipMemsetAsync(colsum, 0, (size_t)B_ * M_ * sizeof(float), stream);
  fused1_kernel<<<19456, 256, 0, stream>>>(Q, K, V, Qb, Kb, Vt, colsum);
  attn_v9_kernel<<<512, 256, 0, stream>>>(Qb, Kb, Vt, colsum, out);
}

// Round 5
// 243.940 us; speedup vs baseline: 1.3115x; 1.3115x over previous
//
#include <hip/hip_runtime.h>
#include <hip/hip_bf16.h>

#define B_  32
#define N_  2048
#define M_  2048
#define D_  128

typedef __attribute__((ext_vector_type(4)))  float f32x4;
typedef __attribute__((ext_vector_type(8)))  short bf16x8;

// log2(e) / sqrt(128): softmax in exp2 domain; folded into Q's bf16 cast.
static constexpr float SCALE2 = 1.4426950408889634f / 11.313708498984761f;

__device__ __forceinline__ unsigned short f2bf(float x) {
  union { float f; unsigned u; } c; c.f = x;
  unsigned u = c.u;
  return (unsigned short)((u + 0x7FFFu + ((u >> 16) & 1u)) >> 16);  // RNE
}

__device__ __forceinline__ unsigned pk2bf(float a, float b) {
  float2 f2; f2.x = a; f2.y = b;
  __hip_bfloat162 h = __float22bfloat162_rn(f2);   // v_cvt_pk_bf16_f32
  union { __hip_bfloat162 h; unsigned u; } c; c.h = h;
  return c.u;
}

__device__ __forceinline__ float fexp2(float x) {
#if __has_builtin(__builtin_amdgcn_exp2f)
  return __builtin_amdgcn_exp2f(x);
#else
  float r; asm("v_exp_f32 %0, %1" : "=v"(r) : "v"(x)); return r;
#endif
}
__device__ __forceinline__ float flog2(float x) {
#if __has_builtin(__builtin_amdgcn_logf)
  return __builtin_amdgcn_logf(x);
#else
  float r; asm("v_log_f32 %0, %1" : "=v"(r) : "v"(x)); return r;
#endif
}

// async global->LDS, 16B per lane; LDS dest = wave-uniform base + lane*16
__device__ __forceinline__ void gl2lds16(const void* gp, void* lp) {
  __builtin_amdgcn_global_load_lds(
      (const __attribute__((address_space(1))) unsigned int*)gp,
      (__attribute__((address_space(3))) unsigned int*)lp, 16, 0, 0);
}

// ---------- cast kernel: Q (SCALE2) and K -> bf16, colsum zero ----------
// 4096 blocks: [0,2048) Q, [2048,4096) K. Per thread: 4 INDEPENDENT float4
// loads (64B, MLP=4 for latency hiding) -> 2 uint4 stores (32B).
__global__ __launch_bounds__(256) void cast_qk_kernel(
    const float* __restrict__ Q, const float* __restrict__ K,
    unsigned short* __restrict__ Qb, unsigned short* __restrict__ Kb,
    float* __restrict__ colsum) {
  const int blk = blockIdx.x;
  const bool isK = blk >= 2048;
  const int g = ((isK ? blk - 2048 : blk) << 8) + threadIdx.x;  // 0..524287
  if (!isK && blk < 64)
    reinterpret_cast<float4*>(colsum)[(blk << 8) + threadIdx.x] =
        make_float4(0.f, 0.f, 0.f, 0.f);
  const float4* src = reinterpret_cast<const float4*>(isK ? K : Q) + 4 * (size_t)g;
  uint4* dst = reinterpret_cast<uint4*>(isK ? Kb : Qb) + 2 * (size_t)g;
  const float sc = isK ? 1.0f : SCALE2;
  const float4 v0 = src[0];
  const float4 v1 = src[1];
  const float4 v2 = src[2];
  const float4 v3 = src[3];
  uint4 o0, o1;
  o0.x = pk2bf(v0.x * sc, v0.y * sc); o0.y = pk2bf(v0.z * sc, v0.w * sc);
  o0.z = pk2bf(v1.x * sc, v1.y * sc); o0.w = pk2bf(v1.z * sc, v1.w * sc);
  o1.x = pk2bf(v2.x * sc, v2.y * sc); o1.y = pk2bf(v2.z * sc, v2.w * sc);
  o1.z = pk2bf(v3.x * sc, v3.y * sc); o1.w = pk2bf(v3.z * sc, v3.w * sc);
  dst[0] = o0;
  dst[1] = o1;
}

// ---------- V transpose: f32 V[b][m][d] -> bf16 Vt[b][d][m] ----------
// 2048 blocks = (M/64=32) x (D/64=2) x (B=32).
__global__ __launch_bounds__(256) void transpose_v_kernel(
    const float* __restrict__ V, unsigned short* __restrict__ Vt) {
  const int idx = blockIdx.x;
  const int b  = idx >> 6;
  const int m0 = ((idx >> 1) & 31) * 64;
  const int d0 = (idx & 1) * 64;
  __shared__ float t[64][65];
  const int tid = threadIdx.x;
  const int r = tid >> 2;   // 0..63
  const int c = tid & 3;    // 0..3
  const float* src = V + ((size_t)b * M_ + (m0 + r)) * D_ + d0 + c * 16;
  #pragma unroll
  for (int i = 0; i < 4; ++i) {
    float4 v = reinterpret_cast<const float4*>(src)[i];
    t[r][c * 16 + i * 4 + 0] = v.x;
    t[r][c * 16 + i * 4 + 1] = v.y;
    t[r][c * 16 + i * 4 + 2] = v.z;
    t[r][c * 16 + i * 4 + 3] = v.w;
  }
  __syncthreads();
  ushort4 ob[4];
  #pragma unroll
  for (int i = 0; i < 4; ++i) {
    ob[i].x = f2bf(t[c * 16 + i * 4 + 0][r]);
    ob[i].y = f2bf(t[c * 16 + i * 4 + 1][r]);
    ob[i].z = f2bf(t[c * 16 + i * 4 + 2][r]);
    ob[i].w = f2bf(t[c * 16 + i * 4 + 3][r]);
  }
  ushort4* dst = reinterpret_cast<ushort4*>(
      Vt + ((size_t)b * D_ + d0 + r) * M_ + m0 + c * 16);
  #pragma unroll
  for (int i = 0; i < 4; ++i) dst[i] = ob[i];
}

// ---------- pass 1: colsum[b][m] += sum_{n in half} 2^(s2[n,m]-16) ----------
// VERBATIM v9 (passed R3, bounded <=88us). 1024 blocks (4/CU): id = x*64 +
// (2b+y); id%8 == (2b+y)%8 so the 16 m-blocks sharing a (b, n-half) Q stripe
// co-reside on one XCD. 32 m/wave (kf = 32 VGPRs, no spill), 2-phase
// double-buffered staging, 16 chunks of 64 n.
__global__ __launch_bounds__(256, 2) void colstats_v9_kernel(
    const unsigned short* __restrict__ Qb, const unsigned short* __restrict__ Kb,
    float* __restrict__ colsum) {
  const int id   = blockIdx.x;          // 0..1023
  const int x    = id >> 6;             // m-block 0..15
  const int q    = id & 63;
  const int b    = q >> 1;
  const int y    = q & 1;               // n-half
  const int lane = threadIdx.x & 63;
  const int l15  = lane & 15;
  const int quad = lane >> 4;
  const int mw   = x * 128 + (threadIdx.x >> 6) * 32;
  const int nbase = y * (N_ / 2);       // 1024-n stripe

  __shared__ unsigned short qbuf[2][64 * 128];  // 2 x 16 KB; rows n, chunk c^(n&15)

  // B-operand: B[col=m=mw+cg*16+l15][k=quad*8+j (+kc*32)] — 32 VGPRs
  bf16x8 kf[2][4];
  #pragma unroll
  for (int cg = 0; cg < 2; ++cg) {
    const unsigned short* Kr =
        Kb + ((size_t)b * M_ + mw + cg * 16 + l15) * D_ + quad * 8;
    #pragma unroll
    for (int kc = 0; kc < 4; ++kc)
      kf[cg][kc] = *reinterpret_cast<const bf16x8*>(Kr + kc * 32);
  }

  // hoisted LDS read bases: addr = pq[kc] + cb*8192 + ng*2048 (u16)
  const unsigned short* pq[4];
  #pragma unroll
  for (int kc = 0; kc < 4; ++kc)
    pq[kc] = qbuf[0] + l15 * 128 + (((kc * 4 + quad) ^ l15) * 8);

  // running DMA source pointers (4 slots/thread), constant LDS dests
  const unsigned short* qg[4];
  unsigned short* ql[4];
  #pragma unroll
  for (int i = 0; i < 4; ++i) {
    int s = i * 256 + threadIdx.x;             // 16B slot 0..1023
    int r = s >> 4, c = (s & 15) ^ (r & 15);
    qg[i] = Qb + ((size_t)b * N_ + nbase + r) * D_ + c * 8;
    ql[i] = qbuf[0] + (size_t)s * 8;           // s*16 bytes
  }

  float psum[2] = {0.f, 0.f};

#define CS_STAGE(nb)                                                          \
  { _Pragma("unroll")                                                         \
    for (int i = 0; i < 4; ++i) {                                             \
      gl2lds16(qg[i], ql[i] + (nb) * (64 * 128));                             \
      qg[i] += 64 * D_;                                                       \
    } }

#define CS_COMPUTE(cb)                                                        \
  { _Pragma("unroll")                                                         \
    for (int ng = 0; ng < 4; ++ng) {                                          \
      f32x4 acc[2] = {{0.f,0.f,0.f,0.f}, {0.f,0.f,0.f,0.f}};                  \
      __builtin_amdgcn_s_setprio(1);                                          \
      _Pragma("unroll")                                                       \
      for (int kc = 0; kc < 4; ++kc) {                                        \
        bf16x8 af = *reinterpret_cast<const bf16x8*>(                         \
            pq[kc] + (cb) * (64 * 128) + ng * 2048);                          \
        _Pragma("unroll")                                                     \
        for (int cg = 0; cg < 2; ++cg)                                        \
          acc[cg] = __builtin_amdgcn_mfma_f32_16x16x32_bf16(                  \
              af, kf[cg][kc], acc[cg], 0, 0, 0);                              \
      }                                                                       \
      __builtin_amdgcn_s_setprio(0);                                          \
      _Pragma("unroll")                                                       \
      for (int cg = 0; cg < 2; ++cg)                                          \
        psum[cg] += fexp2(acc[cg][0] - 16.f) + fexp2(acc[cg][1] - 16.f) +     \
                    fexp2(acc[cg][2] - 16.f) + fexp2(acc[cg][3] - 16.f);      \
    } }

  CS_STAGE(0);                                 // chunk 0
  __syncthreads();
  #pragma unroll 1
  for (int it = 0; it < 16; it += 2) {
    CS_STAGE(1);                               // chunk it+1 (<=15 always)
    CS_COMPUTE(0);
    __syncthreads();                           // chunk it+1 landed; buf0 free
    if (it + 2 < 16) CS_STAGE(0);              // chunk it+2
    CS_COMPUTE(1);
    __syncthreads();
  }
#undef CS_STAGE
#undef CS_COMPUTE

  #pragma unroll
  for (int cg = 0; cg < 2; ++cg) {
    psum[cg] += __shfl_xor(psum[cg], 16);
    psum[cg] += __shfl_xor(psum[cg], 32);
  }
  if (quad == 0) {
    #pragma unroll
    for (int cg = 0; cg < 2; ++cg)
      atomicAdd(colsum + (size_t)b * M_ + mw + cg * 16 + l15, psum[cg]);
  }
}

// ---------- pass 2: O[n,d] = sum_m 2^(s2[n,m]-cml[m]) * Vt[d,m] ----------
// VERBATIM v9 (proven 87.9us, MfmaUtil 33%, FETCH 24.7MB). 512 blocks,
// XCD-swizzled (id%8==b%8). 64-m chunks, double-buffered K/V LDS, 2-phase
// schedule, one barrier per chunk, setprio around MFMA clusters.
__global__ __launch_bounds__(256, 2) void attn_v9_kernel(
    const unsigned short* __restrict__ Qb, const unsigned short* __restrict__ Kb,
    const unsigned short* __restrict__ Vt, const float* __restrict__ colsum,
    float* __restrict__ out) {
  const int id   = blockIdx.x;        // 0..511
  const int b    = id & 31;
  const int xq   = id >> 5;           // n-block 0..15
  const int wv   = threadIdx.x >> 6;  // 0..3
  const int lane = threadIdx.x & 63;
  const int l15  = lane & 15;
  const int quad = lane >> 4;
  const int nq   = xq * 128 + wv * 32;

  __shared__ unsigned short kbuf[2][64 * 128];  // 2x16 KB: rows m (256B), chunk c^(m&15)
  __shared__ unsigned short vbuf[2][128 * 64];  // 2x16 KB: rows d (128B), chunk c^(d&7)
  __shared__ unsigned short pbuf[4][32 * 40];   // 10 KB: per-wave P^T [n][m32], stride 80B
  __shared__ float cmlb[2][64];                 // per-chunk log2 column denominators

  // Q B-operand: B[col=n=ng*16+l15][k=quad*8+j (+kc*32)] — loop invariant
  bf16x8 qf[2][4];
  #pragma unroll
  for (int ng = 0; ng < 2; ++ng) {
    const unsigned short* Qr =
        Qb + ((size_t)b * N_ + nq + ng * 16 + l15) * D_ + quad * 8;
    #pragma unroll
    for (int kc = 0; kc < 4; ++kc)
      qf[ng][kc] = *reinterpret_cast<const bf16x8*>(Qr + kc * 32);
  }

  // hoisted LDS bases (u16 units)
  const unsigned short* pk[4];   // K read: + cb*8192 + sub*4096 + cg*2048
  #pragma unroll
  for (int kc = 0; kc < 4; ++kc)
    pk[kc] = kbuf[0] + l15 * 128 + (((kc * 4 + quad) ^ l15) * 8);
  const unsigned short* pv[2];   // V read: + cb*8192 + dt*1024
  #pragma unroll
  for (int sub = 0; sub < 2; ++sub)
    pv[sub] = vbuf[0] + l15 * 64 + (((sub * 4 + quad) ^ (l15 & 7)) * 8);
  unsigned short* pww[2];        // P write: + cg*16
  const unsigned short* pwr[2];  // P read
  #pragma unroll
  for (int ng = 0; ng < 2; ++ng) {
    pww[ng] = pbuf[wv] + (ng * 16 + l15) * 40 + quad * 4;
    pwr[ng] = pbuf[wv] + (ng * 16 + l15) * 40 + quad * 8;
  }

  // running DMA source ptrs (4 K + 4 V slots/thread), constant LDS dests
  const unsigned short* kg[4]; unsigned short* kl[4];
  const unsigned short* vg[4]; unsigned short* vl[4];
  #pragma unroll
  for (int i = 0; i < 4; ++i) {
    int s = i * 256 + threadIdx.x;               // 16B slot 0..1023
    int rk = s >> 4, ck = (s & 15) ^ (rk & 15);
    kg[i] = Kb + ((size_t)b * M_ + rk) * D_ + ck * 8;
    kl[i] = kbuf[0] + (size_t)s * 8;
    int rv = s >> 3, cv = (s & 7) ^ (rv & 7);
    vg[i] = Vt + ((size_t)b * D_ + rv) * M_ + cv * 8;
    vl[i] = vbuf[0] + (size_t)s * 8;
  }

  const float* csb = colsum + (size_t)b * M_;

  f32x4 o[2][8];
  #pragma unroll
  for (int ng = 0; ng < 2; ++ng)
    #pragma unroll
    for (int dt = 0; dt < 8; ++dt) o[ng][dt] = (f32x4){0.f, 0.f, 0.f, 0.f};

#define AT_STAGE(nb, chunk)                                                   \
  { _Pragma("unroll")                                                         \
    for (int i = 0; i < 4; ++i) {                                             \
      gl2lds16(kg[i], kl[i] + (nb) * (64 * 128));                             \
      kg[i] += 64 * D_;                                                       \
      gl2lds16(vg[i], vl[i] + (nb) * (128 * 64));                             \
      vg[i] += 64;                                                            \
    }                                                                         \
    if (threadIdx.x < 64)                                                     \
      cmlb[nb][threadIdx.x] =                                                 \
          flog2(csb[(chunk) * 64 + threadIdx.x]) + 16.f; }

#define AT_COMPUTE(cb)                                                        \
  { _Pragma("unroll")                                                         \
    for (int sub = 0; sub < 2; ++sub) {                                       \
      /* QK^T (S^T): sacc[cg][ng]: row m=sub*32+cg*16+quad*4+r, col n */      \
      f32x4 sacc[2][2] = {{{0.f,0.f,0.f,0.f},{0.f,0.f,0.f,0.f}},              \
                          {{0.f,0.f,0.f,0.f},{0.f,0.f,0.f,0.f}}};             \
      __builtin_amdgcn_s_setprio(1);                                          \
      _Pragma("unroll")                                                       \
      for (int kc = 0; kc < 4; ++kc) {                                        \
        _Pragma("unroll")                                                     \
        for (int cg = 0; cg < 2; ++cg) {                                      \
          bf16x8 kfr = *reinterpret_cast<const bf16x8*>(                      \
              pk[kc] + (cb) * (64 * 128) + sub * 4096 + cg * 2048);           \
          sacc[cg][0] = __builtin_amdgcn_mfma_f32_16x16x32_bf16(              \
              kfr, qf[0][kc], sacc[cg][0], 0, 0, 0);                          \
          sacc[cg][1] = __builtin_amdgcn_mfma_f32_16x16x32_bf16(              \
              kfr, qf[1][kc], sacc[cg][1], 0, 0, 0);                          \
        }                                                                     \
      }                                                                       \
      __builtin_amdgcn_s_setprio(0);                                          \
      /* normalized P: w = 2^(s2 - cml[m]); packed b64 of 4 consecutive m */  \
      _Pragma("unroll")                                                       \
      for (int cg = 0; cg < 2; ++cg) {                                        \
        float4 cm4 = *reinterpret_cast<const float4*>(                        \
            &cmlb[cb][sub * 32 + cg * 16 + quad * 4]);                        \
        _Pragma("unroll")                                                     \
        for (int ng = 0; ng < 2; ++ng) {                                      \
          uint2 w;                                                            \
          w.x = pk2bf(fexp2(sacc[cg][ng][0] - cm4.x),                         \
                      fexp2(sacc[cg][ng][1] - cm4.y));                        \
          w.y = pk2bf(fexp2(sacc[cg][ng][2] - cm4.z),                         \
                      fexp2(sacc[cg][ng][3] - cm4.w));                        \
          *reinterpret_cast<uint2*>(pww[ng] + cg * 16) = w;                   \
        }                                                                     \
      }                                                                       \
      /* P A-frags (same-wave LDS RAW; lgkmcnt ordered) */                    \
      bf16x8 pa0 = *reinterpret_cast<const bf16x8*>(pwr[0]);                  \
      bf16x8 pa1 = *reinterpret_cast<const bf16x8*>(pwr[1]);                  \
      __builtin_amdgcn_s_setprio(1);                                          \
      _Pragma("unroll")                                                       \
      for (int dt = 0; dt < 8; ++dt) {                                        \
        bf16x8 vfr = *reinterpret_cast<const bf16x8*>(                        \
            pv[sub] + (cb) * (128 * 64) + dt * 1024);                         \
        o[0][dt] = __builtin_amdgcn_mfma_f32_16x16x32_bf16(                   \
            pa0, vfr, o[0][dt], 0, 0, 0);                                     \
        o[1][dt] = __builtin_amdgcn_mfma_f32_16x16x32_bf16(                   \
            pa1, vfr, o[1][dt], 0, 0, 0);                                     \
      }                                                                       \
      __builtin_amdgcn_s_setprio(0);                                          \
    } }

  AT_STAGE(0, 0);
  __syncthreads();
  #pragma unroll 1
  for (int it = 0; it < 32; it += 2) {
    AT_STAGE(1, it + 1);                       // prefetch while computing cur
    AT_COMPUTE(0);
    __syncthreads();                           // next chunk landed; buf0 free
    if (it + 2 < 32) AT_STAGE(0, it + 2);
    AT_COMPUTE(1);
    __syncthreads();
  }
#undef AT_STAGE
#undef AT_COMPUTE

  // epilogue: o[ng][dt][r] = O[nq + ng*16 + quad*4 + r][dt*16 + l15]
  #pragma unroll
  for (int ng = 0; ng < 2; ++ng)
    #pragma unroll
    for (int dt = 0; dt < 8; ++dt)
      #pragma unroll
      for (int r = 0; r < 4; ++r)
        out[((size_t)b * N_ + nq + ng * 16 + quad * 4 + r) * D_ + dt * 16 + l15] =
            o[ng][dt][r];
}

extern "C" void kernel_launch(void* const* d_in, const int* in_sizes, int n_in,
                              void* d_out, int out_size, void* d_ws, size_t ws_size,
                              hipStream_t stream) {
  const float* Q = (const float*)d_in[0];
  const float* K = (const float*)d_in[1];
  const float* V = (const float*)d_in[2];
  float* out = (float*)d_out;

  const size_t elems = (size_t)B_ * N_ * D_;   // 8,388,608 per tensor
  unsigned short* Qb = (unsigned short*)d_ws;                  // 16 MB
  unsigned short* Kb = Qb + elems;                             // 16 MB
  unsigned short* Vt = Kb + elems;                             // 16 MB
  float* colsum = (float*)(Vt + elems);                        // 256 KB
  // total ws use ~= 48.3 MB (proven safe)

  cast_qk_kernel<<<4096, 256, 0, stream>>>(Q, K, Qb, Kb, colsum);
  transpose_v_kernel<<<2048, 256, 0, stream>>>(V, Vt);
  colstats_v9_kernel<<<1024, 256, 0, stream>>>(Qb, Kb, colsum);
  attn_v9_kernel<<<512, 256, 0, stream>>>(Qb, Kb, Vt, colsum, out);
}